// Round 4
// baseline (2081.282 us; speedup 1.0000x reference)
//
#include <hip/hip_runtime.h>
#include <hip/hip_bf16.h>

#define DFEAT   128
#define BCAP    2048         // edge capacity per 64-node bucket (avg ~1024)
#define NB_MAX  1024

typedef __attribute__((ext_vector_type(8))) short bf16x8;
typedef __attribute__((ext_vector_type(4))) float f32x4;
typedef unsigned int uint;

// ---------------- bucket cursor init: cursor[b] = b * BCAP ----------------

__global__ void cursor_init(int* __restrict__ cursor, int NB) {
    int b = blockIdx.x * 256 + threadIdx.x;
    if (b < NB) cursor[b] = b * BCAP;
}

// ---------------- single-pass dst-bucketed edge scatter ----------------
// bucket = dst >> 6. payload: (src | dstLocal<<26, weight_bits)

__global__ __launch_bounds__(1024) void bin_scatter(const int* __restrict__ src,
                                                    const int* __restrict__ dst,
                                                    const float* __restrict__ ew,
                                                    int* __restrict__ cursor,
                                                    int2* __restrict__ bedges,
                                                    int E, int NB) {
    __shared__ int hist[NB_MAX];
    __shared__ int base[NB_MAX];
    const int tid = threadIdx.x;
    for (int b = tid; b < NB; b += 1024) hist[b] = 0;
    __syncthreads();

    int  s[8]; float w[8]; int bk[8]; int dl[8];
    const int i0 = blockIdx.x * 8192 + tid;
    #pragma unroll
    for (int k = 0; k < 8; ++k) {
        int i = i0 + k * 1024;
        if (i < E) {
            s[k] = src[i]; w[k] = ew[i];
            int d = dst[i];
            bk[k] = d >> 6; dl[k] = d & 63;
            atomicAdd(&hist[bk[k]], 1);
        } else bk[k] = -1;
    }
    __syncthreads();
    for (int b = tid; b < NB; b += 1024) {
        int c = hist[b];
        base[b] = (c > 0) ? atomicAdd(&cursor[b], c) : 0;
        hist[b] = 0;                       // reuse as rank counter
    }
    __syncthreads();
    #pragma unroll
    for (int k = 0; k < 8; ++k) {
        if (bk[k] >= 0) {
            int r = atomicAdd(&hist[bk[k]], 1);
            int pos = base[bk[k]] + r;
            if (pos < ((bk[k] + 1) << 11)) {   // overflow guard (never triggers)
                bedges[pos] = make_int2(s[k] | (dl[k] << 26), __float_as_int(w[k]));
            }
        }
    }
}

// ---------------- f32 -> bf16 conversion ----------------

__device__ __forceinline__ uint pack_bf16x2(float a, float b) {
    __hip_bfloat16 ba = __float2bfloat16(a);
    __hip_bfloat16 bb = __float2bfloat16(b);
    unsigned short ua = *(unsigned short*)&ba;
    unsigned short ub = *(unsigned short*)&bb;
    return (uint)ua | ((uint)ub << 16);
}

__global__ void cvt_kernel(const float* __restrict__ in, uint* __restrict__ out, int n2) {
    int i = blockIdx.x * 256 + threadIdx.x;
    if (i < n2) {
        float2 v = ((const float2*)in)[i];
        out[i] = pack_bf16x2(v.x, v.y);
    }
}

// ------------- weight pack: frag-ordered bf16 for mfma_f32_16x16x32_bf16 -------------
// Bcat[k][n]: k<128 -> wrel[n][k] ; k>=128 -> wroot[n][k-128]
// Bp[((kstep*8 + nfrag)*64 + lane)*8 + j] = Bcat[kstep*32 + (lane>>4)*8 + j][nfrag*16 + (lane&15)]

__global__ void prep_Bpack(const float* __restrict__ wrel, const float* __restrict__ wroot,
                           __hip_bfloat16* __restrict__ Bp) {
    int idx = blockIdx.x * 256 + threadIdx.x;   // 0..32767
    if (idx >= 32768) return;
    int j     = idx & 7;
    int lane  = (idx >> 3) & 63;
    int nfrag = (idx >> 9) & 7;
    int kstep = idx >> 12;
    int k = kstep * 32 + (lane >> 4) * 8 + j;
    int n = nfrag * 16 + (lane & 15);
    float v = (k < 128) ? wrel[n * 128 + k] : wroot[n * 128 + (k - 128)];
    Bp[idx] = __float2bfloat16(v);
}

// ---------------- fused layer: LDS-atomic aggregate -> MFMA GEMM ----------------
// f: [N][64] uint (bf16x2). Block = one 64-node bucket, 1024 threads (16 waves).
// Phase 1: waves split bucket edge list evenly, ds_add_f32 into acc[64][132].
// Phase 2: C[64,128] = [agg | root][64,256] @ Bcat[256,128] + bias  (MFMA).

template<int RELU, int OUTF32>
__global__ __launch_bounds__(1024) void fused_layer(const uint* __restrict__ f,
                                                    const int* __restrict__ cursor,
                                                    const int2* __restrict__ bedges,
                                                    const bf16x8* __restrict__ Bp,
                                                    const float* __restrict__ bias,
                                                    float* __restrict__ outf,
                                                    __hip_bfloat16* __restrict__ outb,
                                                    int N) {
    __shared__ float acc[64][132];
    const int tid  = threadIdx.x;
    const int lane = tid & 63, wid = tid >> 6;     // wid 0..15
    const int b    = blockIdx.x;
    const int tile = b * 64;

    for (int i = tid; i < 64 * 132; i += 1024) ((float*)acc)[i] = 0.f;
    __syncthreads();

    // ---- phase 1: even edge split, 4 edges in flight per wave ----
    const int beg = b << 11;          // b * BCAP
    const int end = cursor[b];
    for (int e0 = beg + wid * 4; e0 < end; e0 += 64) {
        const int cnt = min(4, end - e0);
        int2 ed[4]; uint v[4];
        #pragma unroll
        for (int k = 0; k < 4; ++k) {
            int idx = e0 + k;
            ed[k] = bedges[idx < end ? idx : e0];
        }
        #pragma unroll
        for (int k = 0; k < 4; ++k)
            v[k] = f[(size_t)(ed[k].x & 0x03FFFFFF) * 64 + lane];
        #pragma unroll
        for (int k = 0; k < 4; ++k) {
            if (k < cnt) {                                 // wave-uniform branch
                const int   dl = ((uint)ed[k].x) >> 26;
                const float w  = __int_as_float(ed[k].y);
                const float lo = __uint_as_float(v[k] << 16);
                const float hi = __uint_as_float(v[k] & 0xffff0000u);
                atomicAdd(&acc[dl][2 * lane],     w * lo);
                atomicAdd(&acc[dl][2 * lane + 1], w * hi);
            }
        }
    }
    __syncthreads();

    // ---- phase 2: GEMM, 16 waves as 4x4 (wr: 16-row group, wcol: 32-col group) ----
    const int wr   = wid >> 2;
    const int wcol = wid & 3;
    const int lrow = lane & 15;
    const int lkq  = lane >> 4;

    const float* arow = &acc[wr * 16 + lrow][0];
    int grow = tile + wr * 16 + lrow;
    if (grow >= N) grow = N - 1;
    const short* fb = (const short*)f;

    f32x4 c0 = (f32x4){0.f, 0.f, 0.f, 0.f};
    f32x4 c1 = (f32x4){0.f, 0.f, 0.f, 0.f};

    #pragma unroll
    for (int ks = 0; ks < 8; ++ks) {
        bf16x8 a;
        if (ks < 4) {
            const float* p = arow + ks * 32 + lkq * 8;
            float4 q0 = *(const float4*)p;
            float4 q1 = *(const float4*)(p + 4);
            union { uint4 u; bf16x8 h; } cv;
            cv.u = make_uint4(pack_bf16x2(q0.x, q0.y), pack_bf16x2(q0.z, q0.w),
                              pack_bf16x2(q1.x, q1.y), pack_bf16x2(q1.z, q1.w));
            a = cv.h;
        } else {
            a = *(const bf16x8*)(fb + (size_t)grow * 128 + (ks - 4) * 32 + lkq * 8);
        }
        bf16x8 b0 = Bp[(ks * 8 + (wcol * 2 + 0)) * 64 + lane];
        bf16x8 b1 = Bp[(ks * 8 + (wcol * 2 + 1)) * 64 + lane];
        c0 = __builtin_amdgcn_mfma_f32_16x16x32_bf16(a, b0, c0, 0, 0, 0);
        c1 = __builtin_amdgcn_mfma_f32_16x16x32_bf16(a, b1, c1, 0, 0, 0);
    }

    // ---- epilogue ----
    const int crow = (lane >> 4) * 4;
    const int ccol = lane & 15;
    #pragma unroll
    for (int ni = 0; ni < 2; ++ni) {
        const f32x4 cc = ni ? c1 : c0;
        const int col = wcol * 32 + ni * 16 + ccol;
        const float bv = bias[col];
        #pragma unroll
        for (int r = 0; r < 4; ++r) {
            const int row = tile + wr * 16 + crow + r;
            if (row < N) {
                float v = cc[r] + bv;
                if (RELU) v = fmaxf(v, 0.f);
                if (OUTF32) outf[(size_t)row * 128 + col] = v;
                else        outb[(size_t)row * 128 + col] = __float2bfloat16(v);
            }
        }
    }
}

// ---------------- launch ----------------

extern "C" void kernel_launch(void* const* d_in, const int* in_sizes, int n_in,
                              void* d_out, int out_size, void* d_ws, size_t ws_size,
                              hipStream_t stream) {
    const float* x   = (const float*)d_in[0];
    const int*  eidx = (const int*)d_in[1];
    const float* ew  = (const float*)d_in[2];
    const float* w1r = (const float*)d_in[3];
    const float* w1t = (const float*)d_in[4];
    const float* b1  = (const float*)d_in[5];
    const float* w2r = (const float*)d_in[6];
    const float* w2t = (const float*)d_in[7];
    const float* b2  = (const float*)d_in[8];
    const float* w3r = (const float*)d_in[9];
    const float* w3t = (const float*)d_in[10];
    const float* b3  = (const float*)d_in[11];
    float* out = (float*)d_out;

    const int N  = in_sizes[0] / DFEAT;   // 50000
    const int E  = in_sizes[2];           // 800000
    const int NB = (N + 63) / 64;         // 782 buckets

    char* ws = (char*)d_ws;
    size_t off = 0;
    auto alloc = [&](size_t bytes) -> void* {
        off = (off + 255) & ~(size_t)255;
        void* p = ws + off;
        off += bytes;
        return p;
    };
    int*  cursor = (int*)alloc((size_t)NB * 4);
    int2* bedges = (int2*)alloc((size_t)NB * BCAP * 8);   // 12.8 MB
    __hip_bfloat16* Bp1 = (__hip_bfloat16*)alloc(32768 * 2);
    __hip_bfloat16* Bp2 = (__hip_bfloat16*)alloc(32768 * 2);
    __hip_bfloat16* Bp3 = (__hip_bfloat16*)alloc(32768 * 2);
    uint* xb  = (uint*)alloc((size_t)N * 64 * 4);
    uint* h1b = (uint*)alloc((size_t)N * 64 * 4);
    uint* h2b = (uint*)alloc((size_t)N * 64 * 4);
    (void)ws_size;

    const int* src = eidx;
    const int* dst = eidx + E;

    // bucket edges by dst
    cursor_init<<<(NB + 255) / 256, 256, 0, stream>>>(cursor, NB);
    bin_scatter<<<(E + 8191) / 8192, 1024, 0, stream>>>(src, dst, ew, cursor, bedges, E, NB);

    // feature + weight conversion
    cvt_kernel<<<(N * 64 + 255) / 256, 256, 0, stream>>>(x, xb, N * 64);
    prep_Bpack<<<128, 256, 0, stream>>>(w1r, w1t, Bp1);
    prep_Bpack<<<128, 256, 0, stream>>>(w2r, w2t, Bp2);
    prep_Bpack<<<128, 256, 0, stream>>>(w3r, w3t, Bp3);

    fused_layer<1, 0><<<NB, 1024, 0, stream>>>(xb, cursor, bedges, (const bf16x8*)Bp1,
                                               b1, nullptr, (__hip_bfloat16*)h1b, N);
    fused_layer<1, 0><<<NB, 1024, 0, stream>>>(h1b, cursor, bedges, (const bf16x8*)Bp2,
                                               b2, nullptr, (__hip_bfloat16*)h2b, N);
    fused_layer<0, 1><<<NB, 1024, 0, stream>>>(h2b, cursor, bedges, (const bf16x8*)Bp3,
                                               b3, out, nullptr, N);
}

// Round 5
// 221.868 us; speedup vs baseline: 9.3807x; 9.3807x over previous
//
#include <hip/hip_runtime.h>
#include <hip/hip_bf16.h>

#define DFEAT   128
#define BCAP    2048         // edge capacity per 64-node bucket (avg ~1024, 32 sigma margin)
#define NB_MAX  1024

typedef __attribute__((ext_vector_type(8))) short bf16x8;
typedef __attribute__((ext_vector_type(4))) float f32x4;
typedef unsigned int uint;

// ---------------- bucket cursor init: cursor[b] = b * BCAP ----------------

__global__ void cursor_init(int* __restrict__ cursor, int NB) {
    int b = blockIdx.x * 256 + threadIdx.x;
    if (b < NB) cursor[b] = b * BCAP;
}

// ---------------- single-pass dst-bucketed edge scatter ----------------
// bucket = dst >> 6. payload: (src | dstLocal<<26, weight_bits)

__global__ __launch_bounds__(1024) void bin_scatter(const int* __restrict__ src,
                                                    const int* __restrict__ dst,
                                                    const float* __restrict__ ew,
                                                    int* __restrict__ cursor,
                                                    int2* __restrict__ bedges,
                                                    int E, int NB) {
    __shared__ int hist[NB_MAX];
    __shared__ int base[NB_MAX];
    const int tid = threadIdx.x;
    for (int b = tid; b < NB; b += 1024) hist[b] = 0;
    __syncthreads();

    int  s[8]; float w[8]; int bk[8]; int dl[8];
    const int i0 = blockIdx.x * 8192 + tid;
    #pragma unroll
    for (int k = 0; k < 8; ++k) {
        int i = i0 + k * 1024;
        if (i < E) {
            s[k] = src[i]; w[k] = ew[i];
            int d = dst[i];
            bk[k] = d >> 6; dl[k] = d & 63;
            atomicAdd(&hist[bk[k]], 1);
        } else bk[k] = -1;
    }
    __syncthreads();
    for (int b = tid; b < NB; b += 1024) {
        int c = hist[b];
        base[b] = (c > 0) ? atomicAdd(&cursor[b], c) : 0;
        hist[b] = 0;                       // reuse as rank counter
    }
    __syncthreads();
    #pragma unroll
    for (int k = 0; k < 8; ++k) {
        if (bk[k] >= 0) {
            int r = atomicAdd(&hist[bk[k]], 1);
            int pos = base[bk[k]] + r;
            if (pos < ((bk[k] + 1) << 11)) {   // overflow guard (never triggers)
                bedges[pos] = make_int2(s[k] | (dl[k] << 26), __float_as_int(w[k]));
            }
        }
    }
}

// ---------------- per-bucket LDS counting sort (in place) + rowptr/rowend ----------------

__global__ __launch_bounds__(1024) void bucket_sort(const int* __restrict__ cursor,
                                                    int2* __restrict__ bedges,
                                                    int* __restrict__ rowptr,
                                                    int* __restrict__ rowend, int N) {
    __shared__ int2 buf[BCAP];                 // 16 KB
    __shared__ int hist[64], pref[64], rank[64];
    const int b = blockIdx.x, tid = threadIdx.x;
    const int base = b << 11;                  // b * BCAP
    const int cnt = cursor[b] - base;

    if (tid < 64) hist[tid] = 0;
    __syncthreads();
    for (int i = tid; i < cnt; i += 1024) {
        int2 e = bedges[base + i];
        buf[i] = e;
        atomicAdd(&hist[((uint)e.x) >> 26], 1);
    }
    __syncthreads();
    if (tid < 64) {
        int v = hist[tid];
        int s = v;
        #pragma unroll
        for (int off = 1; off < 64; off <<= 1) {
            int t = __shfl_up(s, off, 64);
            if (tid >= off) s += t;
        }
        pref[tid] = s - v;                     // exclusive prefix
        rank[tid] = 0;
        int node = b * 64 + tid;
        if (node < N) {
            rowptr[node] = base + (s - v);
            rowend[node] = base + s;
        }
    }
    __syncthreads();
    for (int i = tid; i < cnt; i += 1024) {
        int2 e = buf[i];
        int dl = ((uint)e.x) >> 26;
        int r = atomicAdd(&rank[dl], 1);
        bedges[base + pref[dl] + r] = e;
    }
}

// ---------------- f32 -> bf16 conversion ----------------

__device__ __forceinline__ uint pack_bf16x2(float a, float b) {
    __hip_bfloat16 ba = __float2bfloat16(a);
    __hip_bfloat16 bb = __float2bfloat16(b);
    unsigned short ua = *(unsigned short*)&ba;
    unsigned short ub = *(unsigned short*)&bb;
    return (uint)ua | ((uint)ub << 16);
}

__global__ void cvt_kernel(const float* __restrict__ in, uint* __restrict__ out, int n2) {
    int i = blockIdx.x * 256 + threadIdx.x;
    if (i < n2) {
        float2 v = ((const float2*)in)[i];
        out[i] = pack_bf16x2(v.x, v.y);
    }
}

// ------------- weight pack: frag-ordered bf16 for mfma_f32_16x16x32_bf16 -------------
// Bcat[k][n]: k<128 -> wrel[n][k] ; k>=128 -> wroot[n][k-128]
// Bp[((kstep*8 + nfrag)*64 + lane)*8 + j] = Bcat[kstep*32 + (lane>>4)*8 + j][nfrag*16 + (lane&15)]

__global__ void prep_Bpack(const float* __restrict__ wrel, const float* __restrict__ wroot,
                           __hip_bfloat16* __restrict__ Bp) {
    int idx = blockIdx.x * 256 + threadIdx.x;   // 0..32767
    if (idx >= 32768) return;
    int j     = idx & 7;
    int lane  = (idx >> 3) & 63;
    int nfrag = (idx >> 9) & 7;
    int kstep = idx >> 12;
    int k = kstep * 32 + (lane >> 4) * 8 + j;
    int n = nfrag * 16 + (lane & 15);
    float v = (k < 128) ? wrel[n * 128 + k] : wroot[n * 128 + (k - 128)];
    Bp[idx] = __float2bfloat16(v);
}

// ---------------- aggregation: 2 nodes per wave, 4-wide each (8 gathers in flight) ------
// f: [N][64] uint (bf16x2).  aggB: [N][64] uint bf16 agg output.

__global__ __launch_bounds__(256) void aggregate_bf16(const uint* __restrict__ f,
                                                      const int* __restrict__ rowptr,
                                                      const int* __restrict__ rowend,
                                                      const int2* __restrict__ bedges,
                                                      uint* __restrict__ aggB, int N) {
    const int wid = threadIdx.x >> 6, lane = threadIdx.x & 63;
    const int nA = blockIdx.x * 8 + wid * 2;
    if (nA >= N) return;
    const int nB = nA + 1;
    const bool hasB = (nB < N);

    int ia = rowptr[nA];
    const int ae = rowend[nA];
    int ib = hasB ? rowptr[nB] : 0;
    const int be = hasB ? rowend[nB] : 0;
    const int a0 = ia, b0 = ib;

    float Ax[4] = {0.f, 0.f, 0.f, 0.f}, Ay[4] = {0.f, 0.f, 0.f, 0.f};
    float Bx[4] = {0.f, 0.f, 0.f, 0.f}, By[4] = {0.f, 0.f, 0.f, 0.f};

    while (ia < ae || ib < be) {
        int2 eA[4], eB[4];
        #pragma unroll
        for (int k = 0; k < 4; ++k) { int i = ia + k; eA[k] = bedges[i < ae ? i : a0]; }
        #pragma unroll
        for (int k = 0; k < 4; ++k) { int i = ib + k; eB[k] = bedges[i < be ? i : b0]; }
        uint vA[4], vB[4]; float wA[4], wB[4];
        #pragma unroll
        for (int k = 0; k < 4; ++k) {
            bool va = (ia + k) < ae;
            int  sa = va ? (eA[k].x & 0x03FFFFFF) : 0;
            vA[k] = f[(size_t)sa * 64 + lane];
            wA[k] = va ? __int_as_float(eA[k].y) : 0.f;
        }
        #pragma unroll
        for (int k = 0; k < 4; ++k) {
            bool vb = (ib + k) < be;
            int  sb = vb ? (eB[k].x & 0x03FFFFFF) : 0;
            vB[k] = f[(size_t)sb * 64 + lane];
            wB[k] = vb ? __int_as_float(eB[k].y) : 0.f;
        }
        #pragma unroll
        for (int k = 0; k < 4; ++k) {
            Ax[k] = fmaf(wA[k], __uint_as_float(vA[k] << 16), Ax[k]);
            Ay[k] = fmaf(wA[k], __uint_as_float(vA[k] & 0xffff0000u), Ay[k]);
            Bx[k] = fmaf(wB[k], __uint_as_float(vB[k] << 16), Bx[k]);
            By[k] = fmaf(wB[k], __uint_as_float(vB[k] & 0xffff0000u), By[k]);
        }
        ia += 4; ib += 4;
    }
    float ax = (Ax[0] + Ax[1]) + (Ax[2] + Ax[3]);
    float ay = (Ay[0] + Ay[1]) + (Ay[2] + Ay[3]);
    aggB[(size_t)nA * 64 + lane] = pack_bf16x2(ax, ay);
    if (hasB) {
        float bx = (Bx[0] + Bx[1]) + (Bx[2] + Bx[3]);
        float by = (By[0] + By[1]) + (By[2] + By[3]);
        aggB[(size_t)nB * 64 + lane] = pack_bf16x2(bx, by);
    }
}

// ---------------- MFMA GEMM: C[M,128] = [agg|root][M,256] @ Bcat[256,128] + bias ----------
// 128x128 block tile, 4 waves (2x2), each wave 64x64 = 4x4 frags, K-loop 8 x 32.

template<int RELU, int OUTF32>
__global__ __launch_bounds__(256) void gemm_mfma(const uint* __restrict__ Aagg,
                                                 const uint* __restrict__ f,
                                                 const bf16x8* __restrict__ Bp,
                                                 const float* __restrict__ bias,
                                                 float* __restrict__ outf,
                                                 __hip_bfloat16* __restrict__ outb, int M) {
    const int tid  = threadIdx.x;
    const int lane = tid & 63, wid = tid >> 6;
    const int wr = wid >> 1, wc = wid & 1;
    const int m0 = blockIdx.x * 128 + wr * 64;
    const int n0 = wc * 64;

    f32x4 acc[4][4];
    #pragma unroll
    for (int mi = 0; mi < 4; ++mi)
        #pragma unroll
        for (int ni = 0; ni < 4; ++ni) acc[mi][ni] = (f32x4){0.f, 0.f, 0.f, 0.f};

    const short* Aa = (const short*)Aagg;
    const short* Ar = (const short*)f;
    const int lrow = lane & 15;
    const int lk   = (lane >> 4) * 8;
    int rowidx[4];
    #pragma unroll
    for (int mi = 0; mi < 4; ++mi) {
        int r = m0 + mi * 16 + lrow;
        rowidx[mi] = (r < M) ? r : (M - 1);
    }

    #pragma unroll
    for (int ks = 0; ks < 8; ++ks) {
        const short* Abase = (ks < 4) ? Aa : Ar;
        const int koff = (ks & 3) * 32 + lk;
        bf16x8 a[4], b[4];
        #pragma unroll
        for (int mi = 0; mi < 4; ++mi)
            a[mi] = *(const bf16x8*)(Abase + (size_t)rowidx[mi] * 128 + koff);
        #pragma unroll
        for (int ni = 0; ni < 4; ++ni)
            b[ni] = Bp[(ks * 8 + (wc * 4 + ni)) * 64 + lane];
        #pragma unroll
        for (int mi = 0; mi < 4; ++mi)
            #pragma unroll
            for (int ni = 0; ni < 4; ++ni)
                acc[mi][ni] = __builtin_amdgcn_mfma_f32_16x16x32_bf16(a[mi], b[ni], acc[mi][ni], 0, 0, 0);
    }

    const int crow = (lane >> 4) * 4;
    const int ccol = lane & 15;
    #pragma unroll
    for (int mi = 0; mi < 4; ++mi) {
        #pragma unroll
        for (int ni = 0; ni < 4; ++ni) {
            int col = n0 + ni * 16 + ccol;
            float bv = bias[col];
            #pragma unroll
            for (int r = 0; r < 4; ++r) {
                int row = m0 + mi * 16 + crow + r;
                if (row < M) {
                    float v = acc[mi][ni][r] + bv;
                    if (RELU) v = fmaxf(v, 0.f);
                    if (OUTF32) outf[(size_t)row * 128 + col] = v;
                    else        outb[(size_t)row * 128 + col] = __float2bfloat16(v);
                }
            }
        }
    }
}

// ---------------- launch ----------------

extern "C" void kernel_launch(void* const* d_in, const int* in_sizes, int n_in,
                              void* d_out, int out_size, void* d_ws, size_t ws_size,
                              hipStream_t stream) {
    const float* x   = (const float*)d_in[0];
    const int*  eidx = (const int*)d_in[1];
    const float* ew  = (const float*)d_in[2];
    const float* w1r = (const float*)d_in[3];
    const float* w1t = (const float*)d_in[4];
    const float* b1  = (const float*)d_in[5];
    const float* w2r = (const float*)d_in[6];
    const float* w2t = (const float*)d_in[7];
    const float* b2  = (const float*)d_in[8];
    const float* w3r = (const float*)d_in[9];
    const float* w3t = (const float*)d_in[10];
    const float* b3  = (const float*)d_in[11];
    float* out = (float*)d_out;

    const int N  = in_sizes[0] / DFEAT;   // 50000
    const int E  = in_sizes[2];           // 800000
    const int NB = (N + 63) / 64;         // 782 buckets

    char* ws = (char*)d_ws;
    size_t off = 0;
    auto alloc = [&](size_t bytes) -> void* {
        off = (off + 255) & ~(size_t)255;
        void* p = ws + off;
        off += bytes;
        return p;
    };
    int*  cursor = (int*)alloc((size_t)NB * 4);
    int*  rowptr = (int*)alloc((size_t)N * 4);
    int*  rowend = (int*)alloc((size_t)N * 4);
    int2* bedges = (int2*)alloc((size_t)NB * BCAP * 8);   // 12.8 MB
    __hip_bfloat16* Bp1 = (__hip_bfloat16*)alloc(32768 * 2);
    __hip_bfloat16* Bp2 = (__hip_bfloat16*)alloc(32768 * 2);
    __hip_bfloat16* Bp3 = (__hip_bfloat16*)alloc(32768 * 2);
    uint* xb   = (uint*)alloc((size_t)N * 64 * 4);
    uint* aggB = (uint*)alloc((size_t)N * 64 * 4);
    uint* h1b  = (uint*)alloc((size_t)N * 64 * 4);
    uint* h2b  = (uint*)alloc((size_t)N * 64 * 4);
    (void)ws_size;

    const int* src = eidx;
    const int* dst = eidx + E;

    // CSR build: bucket scatter + per-bucket counting sort
    cursor_init<<<(NB + 255) / 256, 256, 0, stream>>>(cursor, NB);
    bin_scatter<<<(E + 8191) / 8192, 1024, 0, stream>>>(src, dst, ew, cursor, bedges, E, NB);
    bucket_sort<<<NB, 1024, 0, stream>>>(cursor, bedges, rowptr, rowend, N);

    // feature + weight conversion
    cvt_kernel<<<(N * 64 + 255) / 256, 256, 0, stream>>>(x, xb, N * 64);
    prep_Bpack<<<128, 256, 0, stream>>>(w1r, w1t, Bp1);
    prep_Bpack<<<128, 256, 0, stream>>>(w2r, w2t, Bp2);
    prep_Bpack<<<128, 256, 0, stream>>>(w3r, w3t, Bp3);

    const int aggGrid  = (N + 7) / 8;
    const int gemmGrid = (N + 127) / 128;

    aggregate_bf16<<<aggGrid, 256, 0, stream>>>(xb, rowptr, rowend, bedges, aggB, N);
    gemm_mfma<1, 0><<<gemmGrid, 256, 0, stream>>>(aggB, xb, (const bf16x8*)Bp1,
                                                  b1, nullptr, (__hip_bfloat16*)h1b, N);
    aggregate_bf16<<<aggGrid, 256, 0, stream>>>(h1b, rowptr, rowend, bedges, aggB, N);
    gemm_mfma<1, 0><<<gemmGrid, 256, 0, stream>>>(aggB, h1b, (const bf16x8*)Bp2,
                                                  b2, nullptr, (__hip_bfloat16*)h2b, N);
    aggregate_bf16<<<aggGrid, 256, 0, stream>>>(h2b, rowptr, rowend, bedges, aggB, N);
    gemm_mfma<0, 1><<<gemmGrid, 256, 0, stream>>>(aggB, h2b, (const bf16x8*)Bp3,
                                                  b3, out, nullptr, N);
}

// Round 6
// 181.849 us; speedup vs baseline: 11.4451x; 1.2201x over previous
//
#include <hip/hip_runtime.h>
#include <hip/hip_bf16.h>

#define DFEAT   128
#define BCAP    2048         // edge capacity per 64-node bucket (avg ~1024, 32 sigma margin)
#define NB_MAX  1024

typedef __attribute__((ext_vector_type(8))) short bf16x8;
typedef __attribute__((ext_vector_type(4))) float f32x4;
typedef unsigned int uint;

// ---------------- bucket cursor init: cursor[b] = b * BCAP ----------------

__global__ void cursor_init(int* __restrict__ cursor, int NB) {
    int b = blockIdx.x * 256 + threadIdx.x;
    if (b < NB) cursor[b] = b * BCAP;
}

// ---------------- single-pass dst-bucketed edge scatter ----------------
// bucket = dst >> 6. payload: (src | dstLocal<<26, weight_bits)

__global__ __launch_bounds__(1024) void bin_scatter(const int* __restrict__ src,
                                                    const int* __restrict__ dst,
                                                    const float* __restrict__ ew,
                                                    int* __restrict__ cursor,
                                                    int2* __restrict__ bedges,
                                                    int E, int NB) {
    __shared__ int hist[NB_MAX];
    __shared__ int base[NB_MAX];
    const int tid = threadIdx.x;
    for (int b = tid; b < NB; b += 1024) hist[b] = 0;
    __syncthreads();

    int  s[8]; float w[8]; int bk[8]; int dl[8];
    const int i0 = blockIdx.x * 8192 + tid;
    #pragma unroll
    for (int k = 0; k < 8; ++k) {
        int i = i0 + k * 1024;
        if (i < E) {
            s[k] = src[i]; w[k] = ew[i];
            int d = dst[i];
            bk[k] = d >> 6; dl[k] = d & 63;
            atomicAdd(&hist[bk[k]], 1);
        } else bk[k] = -1;
    }
    __syncthreads();
    for (int b = tid; b < NB; b += 1024) {
        int c = hist[b];
        base[b] = (c > 0) ? atomicAdd(&cursor[b], c) : 0;
        hist[b] = 0;                       // reuse as rank counter
    }
    __syncthreads();
    #pragma unroll
    for (int k = 0; k < 8; ++k) {
        if (bk[k] >= 0) {
            int r = atomicAdd(&hist[bk[k]], 1);
            int pos = base[bk[k]] + r;
            if (pos < ((bk[k] + 1) << 11)) {   // overflow guard (never triggers)
                bedges[pos] = make_int2(s[k] | (dl[k] << 26), __float_as_int(w[k]));
            }
        }
    }
}

// ---------------- per-bucket LDS counting sort (in place) + rowptr/rowend ----------------

__global__ __launch_bounds__(1024) void bucket_sort(const int* __restrict__ cursor,
                                                    int2* __restrict__ bedges,
                                                    int* __restrict__ rowptr,
                                                    int* __restrict__ rowend, int N) {
    __shared__ int2 buf[BCAP];                 // 16 KB
    __shared__ int hist[64], pref[64], rank[64];
    const int b = blockIdx.x, tid = threadIdx.x;
    const int base = b << 11;                  // b * BCAP
    const int cnt = cursor[b] - base;

    if (tid < 64) hist[tid] = 0;
    __syncthreads();
    for (int i = tid; i < cnt; i += 1024) {
        int2 e = bedges[base + i];
        buf[i] = e;
        atomicAdd(&hist[((uint)e.x) >> 26], 1);
    }
    __syncthreads();
    if (tid < 64) {
        int v = hist[tid];
        int s = v;
        #pragma unroll
        for (int off = 1; off < 64; off <<= 1) {
            int t = __shfl_up(s, off, 64);
            if (tid >= off) s += t;
        }
        pref[tid] = s - v;                     // exclusive prefix
        rank[tid] = 0;
        int node = b * 64 + tid;
        if (node < N) {
            rowptr[node] = base + (s - v);
            rowend[node] = base + s;
        }
    }
    __syncthreads();
    for (int i = tid; i < cnt; i += 1024) {
        int2 e = buf[i];
        int dl = ((uint)e.x) >> 26;
        int r = atomicAdd(&rank[dl], 1);
        bedges[base + pref[dl] + r] = e;
    }
}

// ---------------- f32 -> bf16 conversion ----------------

__device__ __forceinline__ uint pack_bf16x2(float a, float b) {
    __hip_bfloat16 ba = __float2bfloat16(a);
    __hip_bfloat16 bb = __float2bfloat16(b);
    unsigned short ua = *(unsigned short*)&ba;
    unsigned short ub = *(unsigned short*)&bb;
    return (uint)ua | ((uint)ub << 16);
}

__global__ void cvt_kernel(const float* __restrict__ in, uint* __restrict__ out, int n2) {
    int i = blockIdx.x * 256 + threadIdx.x;
    if (i < n2) {
        float2 v = ((const float2*)in)[i];
        out[i] = pack_bf16x2(v.x, v.y);
    }
}

// ------------- weight pack: frag-ordered bf16 for mfma_f32_16x16x32_bf16 -------------
// Bcat[k][n]: k<128 -> wrel[n][k] ; k>=128 -> wroot[n][k-128]
// Bp[((kstep*8 + nfrag)*64 + lane)*8 + j] = Bcat[kstep*32 + (lane>>4)*8 + j][nfrag*16 + (lane&15)]

__global__ void prep_Bpack(const float* __restrict__ wrel, const float* __restrict__ wroot,
                           __hip_bfloat16* __restrict__ Bp) {
    int idx = blockIdx.x * 256 + threadIdx.x;   // 0..32767
    if (idx >= 32768) return;
    int j     = idx & 7;
    int lane  = (idx >> 3) & 63;
    int nfrag = (idx >> 9) & 7;
    int kstep = idx >> 12;
    int k = kstep * 32 + (lane >> 4) * 8 + j;
    int n = nfrag * 16 + (lane & 15);
    float v = (k < 128) ? wrel[n * 128 + k] : wroot[n * 128 + (k - 128)];
    Bp[idx] = __float2bfloat16(v);
}

// ---------------- aggregation: one wave per node, scalar-broadcast edge loop ----------------
// f: [N][64] uint (bf16x2).  aggB: [N][64] uint bf16 agg output.
// Edge metadata for up to 64 edges loaded in ONE vector load (lane j = edge j),
// then broadcast per edge via readlane -> SGPR src (scalar gather base) + SGPR weight.

__global__ __launch_bounds__(256) void aggregate_bf16(const uint* __restrict__ f,
                                                      const int* __restrict__ rowptr,
                                                      const int* __restrict__ rowend,
                                                      const int2* __restrict__ bedges,
                                                      uint* __restrict__ aggB, int N) {
    const int wid = threadIdx.x >> 6, lane = threadIdx.x & 63;
    const int node = blockIdx.x * 4 + wid;
    if (node >= N) return;
    const int beg = rowptr[node];
    const int deg = rowend[node] - beg;

    float ax0 = 0.f, ay0 = 0.f, ax1 = 0.f, ay1 = 0.f;

    int done = 0;
    while (done < deg) {
        const int chunk = min(deg - done, 64);
        // one load: lane j holds edge metadata for edge (done + j); tail lanes padded w=0
        int2 e = bedges[beg + done + min(lane, chunk - 1)];
        const int vsrc = e.x & 0x03FFFFFF;
        const int vwb  = (lane < chunk) ? e.y : 0;      // 0 bits == 0.0f
        const int iters = (chunk + 3) & ~3;             // <= 64
        for (int j = 0; j < iters; j += 4) {
            const int s0 = __builtin_amdgcn_readlane(vsrc, j + 0);
            const int s1 = __builtin_amdgcn_readlane(vsrc, j + 1);
            const int s2 = __builtin_amdgcn_readlane(vsrc, j + 2);
            const int s3 = __builtin_amdgcn_readlane(vsrc, j + 3);
            const float w0 = __int_as_float(__builtin_amdgcn_readlane(vwb, j + 0));
            const float w1 = __int_as_float(__builtin_amdgcn_readlane(vwb, j + 1));
            const float w2 = __int_as_float(__builtin_amdgcn_readlane(vwb, j + 2));
            const float w3 = __int_as_float(__builtin_amdgcn_readlane(vwb, j + 3));
            const uint v0 = f[(size_t)s0 * 64 + lane];
            const uint v1 = f[(size_t)s1 * 64 + lane];
            const uint v2 = f[(size_t)s2 * 64 + lane];
            const uint v3 = f[(size_t)s3 * 64 + lane];
            ax0 = fmaf(w0, __uint_as_float(v0 << 16), ax0);
            ay0 = fmaf(w0, __uint_as_float(v0 & 0xffff0000u), ay0);
            ax1 = fmaf(w1, __uint_as_float(v1 << 16), ax1);
            ay1 = fmaf(w1, __uint_as_float(v1 & 0xffff0000u), ay1);
            ax0 = fmaf(w2, __uint_as_float(v2 << 16), ax0);
            ay0 = fmaf(w2, __uint_as_float(v2 & 0xffff0000u), ay0);
            ax1 = fmaf(w3, __uint_as_float(v3 << 16), ax1);
            ay1 = fmaf(w3, __uint_as_float(v3 & 0xffff0000u), ay1);
        }
        done += chunk;
    }
    aggB[(size_t)node * 64 + lane] = pack_bf16x2(ax0 + ax1, ay0 + ay1);
}

// ---------------- MFMA GEMM: C[M,128] = [agg|root][M,256] @ Bcat[256,128] + bias ----------
// 128x128 block tile, 4 waves (2x2), each wave 64x64 = 4x4 frags, K-loop 8 x 32.

template<int RELU, int OUTF32>
__global__ __launch_bounds__(256) void gemm_mfma(const uint* __restrict__ Aagg,
                                                 const uint* __restrict__ f,
                                                 const bf16x8* __restrict__ Bp,
                                                 const float* __restrict__ bias,
                                                 float* __restrict__ outf,
                                                 __hip_bfloat16* __restrict__ outb, int M) {
    const int tid  = threadIdx.x;
    const int lane = tid & 63, wid = tid >> 6;
    const int wr = wid >> 1, wc = wid & 1;
    const int m0 = blockIdx.x * 128 + wr * 64;
    const int n0 = wc * 64;

    f32x4 acc[4][4];
    #pragma unroll
    for (int mi = 0; mi < 4; ++mi)
        #pragma unroll
        for (int ni = 0; ni < 4; ++ni) acc[mi][ni] = (f32x4){0.f, 0.f, 0.f, 0.f};

    const short* Aa = (const short*)Aagg;
    const short* Ar = (const short*)f;
    const int lrow = lane & 15;
    const int lk   = (lane >> 4) * 8;
    int rowidx[4];
    #pragma unroll
    for (int mi = 0; mi < 4; ++mi) {
        int r = m0 + mi * 16 + lrow;
        rowidx[mi] = (r < M) ? r : (M - 1);
    }

    #pragma unroll
    for (int ks = 0; ks < 8; ++ks) {
        const short* Abase = (ks < 4) ? Aa : Ar;
        const int koff = (ks & 3) * 32 + lk;
        bf16x8 a[4], b[4];
        #pragma unroll
        for (int mi = 0; mi < 4; ++mi)
            a[mi] = *(const bf16x8*)(Abase + (size_t)rowidx[mi] * 128 + koff);
        #pragma unroll
        for (int ni = 0; ni < 4; ++ni)
            b[ni] = Bp[(ks * 8 + (wc * 4 + ni)) * 64 + lane];
        #pragma unroll
        for (int mi = 0; mi < 4; ++mi)
            #pragma unroll
            for (int ni = 0; ni < 4; ++ni)
                acc[mi][ni] = __builtin_amdgcn_mfma_f32_16x16x32_bf16(a[mi], b[ni], acc[mi][ni], 0, 0, 0);
    }

    const int crow = (lane >> 4) * 4;
    const int ccol = lane & 15;
    #pragma unroll
    for (int mi = 0; mi < 4; ++mi) {
        #pragma unroll
        for (int ni = 0; ni < 4; ++ni) {
            int col = n0 + ni * 16 + ccol;
            float bv = bias[col];
            #pragma unroll
            for (int r = 0; r < 4; ++r) {
                int row = m0 + mi * 16 + crow + r;
                if (row < M) {
                    float v = acc[mi][ni][r] + bv;
                    if (RELU) v = fmaxf(v, 0.f);
                    if (OUTF32) outf[(size_t)row * 128 + col] = v;
                    else        outb[(size_t)row * 128 + col] = __float2bfloat16(v);
                }
            }
        }
    }
}

// ---------------- launch ----------------

extern "C" void kernel_launch(void* const* d_in, const int* in_sizes, int n_in,
                              void* d_out, int out_size, void* d_ws, size_t ws_size,
                              hipStream_t stream) {
    const float* x   = (const float*)d_in[0];
    const int*  eidx = (const int*)d_in[1];
    const float* ew  = (const float*)d_in[2];
    const float* w1r = (const float*)d_in[3];
    const float* w1t = (const float*)d_in[4];
    const float* b1  = (const float*)d_in[5];
    const float* w2r = (const float*)d_in[6];
    const float* w2t = (const float*)d_in[7];
    const float* b2  = (const float*)d_in[8];
    const float* w3r = (const float*)d_in[9];
    const float* w3t = (const float*)d_in[10];
    const float* b3  = (const float*)d_in[11];
    float* out = (float*)d_out;

    const int N  = in_sizes[0] / DFEAT;   // 50000
    const int E  = in_sizes[2];           // 800000
    const int NB = (N + 63) / 64;         // 782 buckets

    char* ws = (char*)d_ws;
    size_t off = 0;
    auto alloc = [&](size_t bytes) -> void* {
        off = (off + 255) & ~(size_t)255;
        void* p = ws + off;
        off += bytes;
        return p;
    };
    int*  cursor = (int*)alloc((size_t)NB * 4);
    int*  rowptr = (int*)alloc((size_t)N * 4);
    int*  rowend = (int*)alloc((size_t)N * 4);
    int2* bedges = (int2*)alloc((size_t)NB * BCAP * 8);   // 12.8 MB
    __hip_bfloat16* Bp1 = (__hip_bfloat16*)alloc(32768 * 2);
    __hip_bfloat16* Bp2 = (__hip_bfloat16*)alloc(32768 * 2);
    __hip_bfloat16* Bp3 = (__hip_bfloat16*)alloc(32768 * 2);
    uint* xb   = (uint*)alloc((size_t)N * 64 * 4);
    uint* aggB = (uint*)alloc((size_t)N * 64 * 4);
    uint* h1b  = (uint*)alloc((size_t)N * 64 * 4);
    uint* h2b  = (uint*)alloc((size_t)N * 64 * 4);
    (void)ws_size;

    const int* src = eidx;
    const int* dst = eidx + E;

    // CSR build: bucket scatter + per-bucket counting sort
    cursor_init<<<(NB + 255) / 256, 256, 0, stream>>>(cursor, NB);
    bin_scatter<<<(E + 8191) / 8192, 1024, 0, stream>>>(src, dst, ew, cursor, bedges, E, NB);
    bucket_sort<<<NB, 1024, 0, stream>>>(cursor, bedges, rowptr, rowend, N);

    // feature + weight conversion
    cvt_kernel<<<(N * 64 + 255) / 256, 256, 0, stream>>>(x, xb, N * 64);
    prep_Bpack<<<128, 256, 0, stream>>>(w1r, w1t, Bp1);
    prep_Bpack<<<128, 256, 0, stream>>>(w2r, w2t, Bp2);
    prep_Bpack<<<128, 256, 0, stream>>>(w3r, w3t, Bp3);

    const int aggGrid  = (N + 3) / 4;
    const int gemmGrid = (N + 127) / 128;

    aggregate_bf16<<<aggGrid, 256, 0, stream>>>(xb, rowptr, rowend, bedges, aggB, N);
    gemm_mfma<1, 0><<<gemmGrid, 256, 0, stream>>>(aggB, xb, (const bf16x8*)Bp1,
                                                  b1, nullptr, (__hip_bfloat16*)h1b, N);
    aggregate_bf16<<<aggGrid, 256, 0, stream>>>(h1b, rowptr, rowend, bedges, aggB, N);
    gemm_mfma<1, 0><<<gemmGrid, 256, 0, stream>>>(aggB, h1b, (const bf16x8*)Bp2,
                                                  b2, nullptr, (__hip_bfloat16*)h2b, N);
    aggregate_bf16<<<aggGrid, 256, 0, stream>>>(h2b, rowptr, rowend, bedges, aggB, N);
    gemm_mfma<0, 1><<<gemmGrid, 256, 0, stream>>>(aggB, h2b, (const bf16x8*)Bp3,
                                                  b3, out, nullptr, N);
}

// Round 7
// 178.295 us; speedup vs baseline: 11.6733x; 1.0199x over previous
//
#include <hip/hip_runtime.h>
#include <hip/hip_bf16.h>

#define DFEAT   128
#define BCAP    2048         // edge capacity per 64-node bucket (avg ~1024, 32 sigma margin)
#define NB_MAX  1024

typedef __attribute__((ext_vector_type(8))) short bf16x8;
typedef __attribute__((ext_vector_type(4))) float f32x4;
typedef unsigned int uint;

// ---------------- bucket cursor init: cursor[b] = b * BCAP ----------------

__global__ void cursor_init(int* __restrict__ cursor, int NB) {
    int b = blockIdx.x * 256 + threadIdx.x;
    if (b < NB) cursor[b] = b * BCAP;
}

// ---------------- single-pass dst-bucketed edge scatter ----------------
// bucket = dst >> 6. payload: (src | dstLocal<<26, weight_bits)

__global__ __launch_bounds__(1024) void bin_scatter(const int* __restrict__ src,
                                                    const int* __restrict__ dst,
                                                    const float* __restrict__ ew,
                                                    int* __restrict__ cursor,
                                                    int2* __restrict__ bedges,
                                                    int E, int NB) {
    __shared__ int hist[NB_MAX];
    __shared__ int base[NB_MAX];
    const int tid = threadIdx.x;
    for (int b = tid; b < NB; b += 1024) hist[b] = 0;
    __syncthreads();

    int  s[8]; float w[8]; int bk[8]; int dl[8];
    const int i0 = blockIdx.x * 8192 + tid;
    #pragma unroll
    for (int k = 0; k < 8; ++k) {
        int i = i0 + k * 1024;
        if (i < E) {
            s[k] = src[i]; w[k] = ew[i];
            int d = dst[i];
            bk[k] = d >> 6; dl[k] = d & 63;
            atomicAdd(&hist[bk[k]], 1);
        } else bk[k] = -1;
    }
    __syncthreads();
    for (int b = tid; b < NB; b += 1024) {
        int c = hist[b];
        base[b] = (c > 0) ? atomicAdd(&cursor[b], c) : 0;
        hist[b] = 0;                       // reuse as rank counter
    }
    __syncthreads();
    #pragma unroll
    for (int k = 0; k < 8; ++k) {
        if (bk[k] >= 0) {
            int r = atomicAdd(&hist[bk[k]], 1);
            int pos = base[bk[k]] + r;
            if (pos < ((bk[k] + 1) << 11)) {   // overflow guard (never triggers)
                bedges[pos] = make_int2(s[k] | (dl[k] << 26), __float_as_int(w[k]));
            }
        }
    }
}

// ---------------- per-bucket LDS counting sort (in place) + rowptr/rowend ----------------

__global__ __launch_bounds__(1024) void bucket_sort(const int* __restrict__ cursor,
                                                    int2* __restrict__ bedges,
                                                    int* __restrict__ rowptr,
                                                    int* __restrict__ rowend, int N) {
    __shared__ int2 buf[BCAP];                 // 16 KB
    __shared__ int hist[64], pref[64], rank[64];
    const int b = blockIdx.x, tid = threadIdx.x;
    const int base = b << 11;                  // b * BCAP
    const int cnt = cursor[b] - base;

    if (tid < 64) hist[tid] = 0;
    __syncthreads();
    for (int i = tid; i < cnt; i += 1024) {
        int2 e = bedges[base + i];
        buf[i] = e;
        atomicAdd(&hist[((uint)e.x) >> 26], 1);
    }
    __syncthreads();
    if (tid < 64) {
        int v = hist[tid];
        int s = v;
        #pragma unroll
        for (int off = 1; off < 64; off <<= 1) {
            int t = __shfl_up(s, off, 64);
            if (tid >= off) s += t;
        }
        pref[tid] = s - v;                     // exclusive prefix
        rank[tid] = 0;
        int node = b * 64 + tid;
        if (node < N) {
            rowptr[node] = base + (s - v);
            rowend[node] = base + s;
        }
    }
    __syncthreads();
    for (int i = tid; i < cnt; i += 1024) {
        int2 e = buf[i];
        int dl = ((uint)e.x) >> 26;
        int r = atomicAdd(&rank[dl], 1);
        bedges[base + pref[dl] + r] = e;
    }
}

// ---------------- f32 -> bf16 conversion ----------------

__device__ __forceinline__ uint pack_bf16x2(float a, float b) {
    __hip_bfloat16 ba = __float2bfloat16(a);
    __hip_bfloat16 bb = __float2bfloat16(b);
    unsigned short ua = *(unsigned short*)&ba;
    unsigned short ub = *(unsigned short*)&bb;
    return (uint)ua | ((uint)ub << 16);
}

__global__ void cvt_kernel(const float* __restrict__ in, uint* __restrict__ out, int n2) {
    int i = blockIdx.x * 256 + threadIdx.x;
    if (i < n2) {
        float2 v = ((const float2*)in)[i];
        out[i] = pack_bf16x2(v.x, v.y);
    }
}

// ------------- weight pack: frag-ordered bf16 for mfma_f32_16x16x32_bf16 -------------
// Bcat[k][n]: k<128 -> wrel[n][k] ; k>=128 -> wroot[n][k-128]
// Bp[((kstep*8 + nfrag)*64 + lane)*8 + j] = Bcat[kstep*32 + (lane>>4)*8 + j][nfrag*16 + (lane&15)]

__global__ void prep_Bpack(const float* __restrict__ wrel, const float* __restrict__ wroot,
                           __hip_bfloat16* __restrict__ Bp) {
    int idx = blockIdx.x * 256 + threadIdx.x;   // 0..32767
    if (idx >= 32768) return;
    int j     = idx & 7;
    int lane  = (idx >> 3) & 63;
    int nfrag = (idx >> 9) & 7;
    int kstep = idx >> 12;
    int k = kstep * 32 + (lane >> 4) * 8 + j;
    int n = nfrag * 16 + (lane & 15);
    float v = (k < 128) ? wrel[n * 128 + k] : wroot[n * 128 + (k - 128)];
    Bp[idx] = __float2bfloat16(v);
}

// ---------------- aggregation: one wave per node, 16 lanes per edge, dwordx4 gathers ----
// f: [N][64] uint (bf16x2) = [N][16] uint4.  aggB: [N][64] uint bf16 agg output.
// grp = lane>>4 picks which edge of a 4-edge quad this lane serves;
// sub = lane&15 picks the 16B slice of that edge's source row.
// Metadata for up to 64 edges is fetched in ONE vector load, then distributed
// per-quad via __shfl (ds_bpermute). 2 quads (8 edges) in flight per iteration.

__global__ __launch_bounds__(256) void aggregate_bf16(const uint* __restrict__ f,
                                                      const int* __restrict__ rowptr,
                                                      const int* __restrict__ rowend,
                                                      const int2* __restrict__ bedges,
                                                      uint* __restrict__ aggB, int N) {
    const int wid = threadIdx.x >> 6, lane = threadIdx.x & 63;
    const int node = blockIdx.x * 4 + wid;
    if (node >= N) return;
    const int beg = rowptr[node];
    const int deg = rowend[node] - beg;
    const int grp = lane >> 4;          // which edge of the quad
    const int sub = lane & 15;          // 16B slice within the row

    const uint4* f4 = (const uint4*)f;  // row = 16 x uint4

    float acc[8];
    #pragma unroll
    for (int i = 0; i < 8; ++i) acc[i] = 0.f;

    int done = 0;
    while (done < deg) {
        const int chunk = min(deg - done, 64);
        // lane j holds metadata for edge (beg+done+j); tail lanes clamped, w=0
        int2 e = bedges[beg + done + min(lane, chunk - 1)];
        const int vsrc = e.x & 0x03FFFFFF;
        const int vwb  = (lane < chunk) ? e.y : 0;      // 0 bits == 0.0f
        const int iters = (chunk + 7) & ~7;             // <= 64
        for (int j = 0; j < iters; j += 8) {
            const int   s0 = __shfl(vsrc, j + grp, 64);
            const float w0 = __int_as_float(__shfl(vwb, j + grp, 64));
            const int   s1 = __shfl(vsrc, j + 4 + grp, 64);
            const float w1 = __int_as_float(__shfl(vwb, j + 4 + grp, 64));
            const uint4 q0 = f4[(size_t)s0 * 16 + sub];
            const uint4 q1 = f4[(size_t)s1 * 16 + sub];
            acc[0] = fmaf(w0, __uint_as_float(q0.x << 16),          acc[0]);
            acc[1] = fmaf(w0, __uint_as_float(q0.x & 0xffff0000u),  acc[1]);
            acc[2] = fmaf(w0, __uint_as_float(q0.y << 16),          acc[2]);
            acc[3] = fmaf(w0, __uint_as_float(q0.y & 0xffff0000u),  acc[3]);
            acc[4] = fmaf(w0, __uint_as_float(q0.z << 16),          acc[4]);
            acc[5] = fmaf(w0, __uint_as_float(q0.z & 0xffff0000u),  acc[5]);
            acc[6] = fmaf(w0, __uint_as_float(q0.w << 16),          acc[6]);
            acc[7] = fmaf(w0, __uint_as_float(q0.w & 0xffff0000u),  acc[7]);
            acc[0] = fmaf(w1, __uint_as_float(q1.x << 16),          acc[0]);
            acc[1] = fmaf(w1, __uint_as_float(q1.x & 0xffff0000u),  acc[1]);
            acc[2] = fmaf(w1, __uint_as_float(q1.y << 16),          acc[2]);
            acc[3] = fmaf(w1, __uint_as_float(q1.y & 0xffff0000u),  acc[3]);
            acc[4] = fmaf(w1, __uint_as_float(q1.z << 16),          acc[4]);
            acc[5] = fmaf(w1, __uint_as_float(q1.z & 0xffff0000u),  acc[5]);
            acc[6] = fmaf(w1, __uint_as_float(q1.w << 16),          acc[6]);
            acc[7] = fmaf(w1, __uint_as_float(q1.w & 0xffff0000u),  acc[7]);
        }
        done += chunk;
    }

    // combine the 4 edge-groups (lanes sharing `sub`)
    #pragma unroll
    for (int i = 0; i < 8; ++i) {
        acc[i] += __shfl_xor(acc[i], 16, 64);
        acc[i] += __shfl_xor(acc[i], 32, 64);
    }

    if (lane < 16) {
        uint4 o;
        o.x = pack_bf16x2(acc[0], acc[1]);
        o.y = pack_bf16x2(acc[2], acc[3]);
        o.z = pack_bf16x2(acc[4], acc[5]);
        o.w = pack_bf16x2(acc[6], acc[7]);
        ((uint4*)aggB)[(size_t)node * 16 + sub] = o;
    }
}

// ---------------- MFMA GEMM: C[M,128] = [agg|root][M,256] @ Bcat[256,128] + bias ----------
// 128x128 block tile, 4 waves (2x2), each wave 64x64 = 4x4 frags, K-loop 8 x 32.

template<int RELU, int OUTF32>
__global__ __launch_bounds__(256) void gemm_mfma(const uint* __restrict__ Aagg,
                                                 const uint* __restrict__ f,
                                                 const bf16x8* __restrict__ Bp,
                                                 const float* __restrict__ bias,
                                                 float* __restrict__ outf,
                                                 __hip_bfloat16* __restrict__ outb, int M) {
    const int tid  = threadIdx.x;
    const int lane = tid & 63, wid = tid >> 6;
    const int wr = wid >> 1, wc = wid & 1;
    const int m0 = blockIdx.x * 128 + wr * 64;
    const int n0 = wc * 64;

    f32x4 acc[4][4];
    #pragma unroll
    for (int mi = 0; mi < 4; ++mi)
        #pragma unroll
        for (int ni = 0; ni < 4; ++ni) acc[mi][ni] = (f32x4){0.f, 0.f, 0.f, 0.f};

    const short* Aa = (const short*)Aagg;
    const short* Ar = (const short*)f;
    const int lrow = lane & 15;
    const int lk   = (lane >> 4) * 8;
    int rowidx[4];
    #pragma unroll
    for (int mi = 0; mi < 4; ++mi) {
        int r = m0 + mi * 16 + lrow;
        rowidx[mi] = (r < M) ? r : (M - 1);
    }

    #pragma unroll
    for (int ks = 0; ks < 8; ++ks) {
        const short* Abase = (ks < 4) ? Aa : Ar;
        const int koff = (ks & 3) * 32 + lk;
        bf16x8 a[4], b[4];
        #pragma unroll
        for (int mi = 0; mi < 4; ++mi)
            a[mi] = *(const bf16x8*)(Abase + (size_t)rowidx[mi] * 128 + koff);
        #pragma unroll
        for (int ni = 0; ni < 4; ++ni)
            b[ni] = Bp[(ks * 8 + (wc * 4 + ni)) * 64 + lane];
        #pragma unroll
        for (int mi = 0; mi < 4; ++mi)
            #pragma unroll
            for (int ni = 0; ni < 4; ++ni)
                acc[mi][ni] = __builtin_amdgcn_mfma_f32_16x16x32_bf16(a[mi], b[ni], acc[mi][ni], 0, 0, 0);
    }

    const int crow = (lane >> 4) * 4;
    const int ccol = lane & 15;
    #pragma unroll
    for (int mi = 0; mi < 4; ++mi) {
        #pragma unroll
        for (int ni = 0; ni < 4; ++ni) {
            int col = n0 + ni * 16 + ccol;
            float bv = bias[col];
            #pragma unroll
            for (int r = 0; r < 4; ++r) {
                int row = m0 + mi * 16 + crow + r;
                if (row < M) {
                    float v = acc[mi][ni][r] + bv;
                    if (RELU) v = fmaxf(v, 0.f);
                    if (OUTF32) outf[(size_t)row * 128 + col] = v;
                    else        outb[(size_t)row * 128 + col] = __float2bfloat16(v);
                }
            }
        }
    }
}

// ---------------- launch ----------------

extern "C" void kernel_launch(void* const* d_in, const int* in_sizes, int n_in,
                              void* d_out, int out_size, void* d_ws, size_t ws_size,
                              hipStream_t stream) {
    const float* x   = (const float*)d_in[0];
    const int*  eidx = (const int*)d_in[1];
    const float* ew  = (const float*)d_in[2];
    const float* w1r = (const float*)d_in[3];
    const float* w1t = (const float*)d_in[4];
    const float* b1  = (const float*)d_in[5];
    const float* w2r = (const float*)d_in[6];
    const float* w2t = (const float*)d_in[7];
    const float* b2  = (const float*)d_in[8];
    const float* w3r = (const float*)d_in[9];
    const float* w3t = (const float*)d_in[10];
    const float* b3  = (const float*)d_in[11];
    float* out = (float*)d_out;

    const int N  = in_sizes[0] / DFEAT;   // 50000
    const int E  = in_sizes[2];           // 800000
    const int NB = (N + 63) / 64;         // 782 buckets

    char* ws = (char*)d_ws;
    size_t off = 0;
    auto alloc = [&](size_t bytes) -> void* {
        off = (off + 255) & ~(size_t)255;
        void* p = ws + off;
        off += bytes;
        return p;
    };
    int*  cursor = (int*)alloc((size_t)NB * 4);
    int*  rowptr = (int*)alloc((size_t)N * 4);
    int*  rowend = (int*)alloc((size_t)N * 4);
    int2* bedges = (int2*)alloc((size_t)NB * BCAP * 8);   // 12.8 MB
    __hip_bfloat16* Bp1 = (__hip_bfloat16*)alloc(32768 * 2);
    __hip_bfloat16* Bp2 = (__hip_bfloat16*)alloc(32768 * 2);
    __hip_bfloat16* Bp3 = (__hip_bfloat16*)alloc(32768 * 2);
    uint* xb   = (uint*)alloc((size_t)N * 64 * 4);
    uint* aggB = (uint*)alloc((size_t)N * 64 * 4);
    uint* h1b  = (uint*)alloc((size_t)N * 64 * 4);
    uint* h2b  = (uint*)alloc((size_t)N * 64 * 4);
    (void)ws_size;

    const int* src = eidx;
    const int* dst = eidx + E;

    // CSR build: bucket scatter + per-bucket counting sort
    cursor_init<<<(NB + 255) / 256, 256, 0, stream>>>(cursor, NB);
    bin_scatter<<<(E + 8191) / 8192, 1024, 0, stream>>>(src, dst, ew, cursor, bedges, E, NB);
    bucket_sort<<<NB, 1024, 0, stream>>>(cursor, bedges, rowptr, rowend, N);

    // feature + weight conversion
    cvt_kernel<<<(N * 64 + 255) / 256, 256, 0, stream>>>(x, xb, N * 64);
    prep_Bpack<<<128, 256, 0, stream>>>(w1r, w1t, Bp1);
    prep_Bpack<<<128, 256, 0, stream>>>(w2r, w2t, Bp2);
    prep_Bpack<<<128, 256, 0, stream>>>(w3r, w3t, Bp3);

    const int aggGrid  = (N + 3) / 4;
    const int gemmGrid = (N + 127) / 128;

    aggregate_bf16<<<aggGrid, 256, 0, stream>>>(xb, rowptr, rowend, bedges, aggB, N);
    gemm_mfma<1, 0><<<gemmGrid, 256, 0, stream>>>(aggB, xb, (const bf16x8*)Bp1,
                                                  b1, nullptr, (__hip_bfloat16*)h1b, N);
    aggregate_bf16<<<aggGrid, 256, 0, stream>>>(h1b, rowptr, rowend, bedges, aggB, N);
    gemm_mfma<1, 0><<<gemmGrid, 256, 0, stream>>>(aggB, h1b, (const bf16x8*)Bp2,
                                                  b2, nullptr, (__hip_bfloat16*)h2b, N);
    aggregate_bf16<<<aggGrid, 256, 0, stream>>>(h2b, rowptr, rowend, bedges, aggB, N);
    gemm_mfma<0, 1><<<gemmGrid, 256, 0, stream>>>(aggB, h2b, (const bf16x8*)Bp3,
                                                  b3, out, nullptr, N);
}